// Round 1
// baseline (66.555 us; speedup 1.0000x reference)
//
#include <hip/hip_runtime.h>

// Problem constants (from reference): N=512, L=16, HOP=8, M=8, C=2, K=6000
#define NN   512
#define LL   16
#define HOPP 8
#define MM   8
#define CC   2
#define KK   6000
#define TT   ((KK - 1) * HOPP + LL)   // 48008

// Block: 256 threads = 4 waves. Wave q handles n in [q*128, q*128+128);
// lane t (0..63) handles k = kb*64 + t. Each thread computes both c values.
__global__ __launch_bounds__(256) void decoder_fused_kernel(
    const float* __restrict__ inputs,    // [M, N, K]
    const float* __restrict__ est_mask,  // [M, C, N, K]
    const float* __restrict__ W,         // [N, L]
    float* __restrict__ out)             // [M, C, T], pre-zeroed
{
    __shared__ float smem[NN * LL];      // 32 KB: W stage, then reduce buffer

    const int tid = threadIdx.x;
    const int t   = tid & 63;            // k-lane within block
    const int q   = tid >> 6;            // n-quarter (wave id)
    const int kb  = blockIdx.x;          // 0..93
    const int m   = blockIdx.y;          // 0..7

    // ---- stage W into LDS (8192 floats, coalesced float4) ----
    for (int j = tid; j < (NN * LL / 4); j += 256) {
        reinterpret_cast<float4*>(smem)[j] =
            reinterpret_cast<const float4*>(W)[j];
    }
    __syncthreads();

    const int k  = kb * 64 + t;
    const int kc = (k < KK) ? k : (KK - 1);   // clamp OOB lanes to a valid addr

    const float* pin = inputs   + (m * NN + q * 128) * KK + kc;
    const float* pm0 = est_mask + ((m * CC + 0) * NN + q * 128) * KK + kc;
    const float* pm1 = pm0 + NN * KK;

    float acc0[LL], acc1[LL];
    #pragma unroll
    for (int l = 0; l < LL; ++l) { acc0[l] = 0.f; acc1[l] = 0.f; }

    const float* wrow = &smem[q * 128 * LL];

    // ---- main loop: 128 n-rows per wave ----
    #pragma unroll 4
    for (int i = 0; i < 128; ++i) {
        const float vin = pin[(size_t)i * KK];
        const float x0  = vin * pm0[(size_t)i * KK];
        const float x1  = vin * pm1[(size_t)i * KK];
        #pragma unroll
        for (int l = 0; l < LL; ++l) {
            const float w = wrow[i * LL + l];     // wave-uniform broadcast
            acc0[l] = fmaf(x0, w, acc0[l]);
            acc1[l] = fmaf(x1, w, acc1[l]);
        }
    }

    // ---- reduce 4 n-quarters -> wave 0 (reuse W's LDS; +1 pad, conflict-free) ----
    __syncthreads();   // everyone done reading W
    if (q > 0) {
        float* dst = &smem[((q - 1) * 64 + t) * 33];
        #pragma unroll
        for (int l = 0; l < LL; ++l) { dst[l] = acc0[l]; dst[16 + l] = acc1[l]; }
    }
    __syncthreads();

    if (q == 0) {
        #pragma unroll
        for (int r = 0; r < 3; ++r) {
            const float* srcp = &smem[(r * 64 + t) * 33];
            #pragma unroll
            for (int l = 0; l < LL; ++l) { acc0[l] += srcp[l]; acc1[l] += srcp[16 + l]; }
        }

        // ---- overlap-and-add: out[8k+j] = lo_k[j] + hi_{k-1}[j] ----
        float ph0[8], ph1[8];
        #pragma unroll
        for (int j = 0; j < 8; ++j) {
            ph0[j] = __shfl_up(acc0[8 + j], 1);
            ph1[j] = __shfl_up(acc1[8 + j], 1);
        }

        if (k < KK) {
            float* o0 = out + (m * CC + 0) * TT;
            float* o1 = out + (m * CC + 1) * TT;
            const int ob = 8 * k;

            if (t == 0) {
                // previous frame owned by another block -> atomic (zeroed base)
                #pragma unroll
                for (int j = 0; j < 8; ++j) {
                    atomicAdd(&o0[ob + j], acc0[j]);
                    atomicAdd(&o1[ob + j], acc1[j]);
                }
            } else {
                #pragma unroll
                for (int j = 0; j < 8; ++j) {
                    o0[ob + j] = acc0[j] + ph0[j];
                    o1[ob + j] = acc1[j] + ph1[j];
                }
            }
            if (t == 63 || k == KK - 1) {
                // hi half consumed by next block (or the tail) -> atomic
                #pragma unroll
                for (int j = 0; j < 8; ++j) {
                    atomicAdd(&o0[ob + 8 + j], acc0[8 + j]);
                    atomicAdd(&o1[ob + 8 + j], acc1[8 + j]);
                }
            }
        }
    }
}

extern "C" void kernel_launch(void* const* d_in, const int* in_sizes, int n_in,
                              void* d_out, int out_size, void* d_ws, size_t ws_size,
                              hipStream_t stream) {
    const float* inputs   = (const float*)d_in[0];  // [8, 512, 6000]
    const float* est_mask = (const float*)d_in[1];  // [8, 2, 512, 6000]
    const float* W        = (const float*)d_in[2];  // [512, 16]
    float*       out      = (float*)d_out;          // [8, 2, 48008]

    hipMemsetAsync(out, 0, (size_t)out_size * sizeof(float), stream);

    dim3 grid((KK + 63) / 64, MM);   // (94, 8) = 752 blocks
    decoder_fused_kernel<<<grid, 256, 0, stream>>>(inputs, est_mask, W, out);
}